// Round 1
// baseline (69.967 us; speedup 1.0000x reference)
//
#include <hip/hip_runtime.h>
#include <hip/hip_bf16.h>

// GCN fused kernel: one wave (64 threads) per batch element.
// B=16384, V=64, F_IN=5, F_HID=3, F_OUT=1
//
// out[b] = ( sum_v relu( dinv[v] * (sum_w adj_hat[v,w] * dinv[w] * X[w,:]) ) ) . W2
// where adj_hat = A + I, dinv = rowsum(adj_hat)^-1/2, X = h0 @ W1.

#define V 64
#define F_IN 5
#define F_HID 3

__global__ __launch_bounds__(64) void gcn_fused_kernel(
    const float* __restrict__ A,     // [B, 64, 64]
    const float* __restrict__ h0,    // [B, 64, 5]
    const float* __restrict__ W1,    // [5, 3]
    const float* __restrict__ W2,    // [3, 1]
    float* __restrict__ out)         // [B]
{
    __shared__ float As[V][V + 1];   // pad 65: bank = (v+w)%32, conflict-free row reads
    __shared__ float4 Xs[V];         // dinv[w]-scaled X row, padded to float4 for broadcast reads
    __shared__ float h0s[V * F_IN];  // staged h0 rows (coalesced global load)

    const int b = blockIdx.x;
    const int t = threadIdx.x;       // 0..63, lane == thread (one wave)

    // ---- Stage A[b] into LDS, coalesced: 16 x (64 lanes x float4) = 16 KB ----
    const float4* A4 = reinterpret_cast<const float4*>(A + (size_t)b * (V * V));
    #pragma unroll
    for (int i = 0; i < 16; ++i) {
        int idx = t + 64 * i;            // float4 index within the 64x64 tile
        float4 v4 = A4[idx];
        int row  = idx >> 4;             // 16 float4 per row
        int col4 = (idx & 15) << 2;
        As[row][col4 + 0] = v4.x;
        As[row][col4 + 1] = v4.y;
        As[row][col4 + 2] = v4.z;
        As[row][col4 + 3] = v4.w;
    }

    // ---- Stage h0[b] (320 floats), coalesced ----
    const float* h0b = h0 + (size_t)b * (V * F_IN);
    #pragma unroll
    for (int i = t; i < V * F_IN; i += 64) h0s[i] = h0b[i];

    __syncthreads();

    // ---- Row sum of adj_hat = A + I  ->  dinv[t] ----
    float rs = 1.0f;                     // identity diagonal contribution
    #pragma unroll
    for (int w = 0; w < V; ++w) rs += As[t][w];
    const float dv = rsqrtf(rs);

    // ---- X[t,:] = h0[t,:] @ W1, scaled by dinv[t] ----
    float x0 = 0.f, x1 = 0.f, x2 = 0.f;
    #pragma unroll
    for (int i = 0; i < F_IN; ++i) {
        float h = h0s[t * F_IN + i];
        x0 += h * W1[i * F_HID + 0];
        x1 += h * W1[i * F_HID + 1];
        x2 += h * W1[i * F_HID + 2];
    }
    Xs[t] = make_float4(dv * x0, dv * x1, dv * x2, 0.f);

    __syncthreads();

    // ---- t[f] = sum_w A[t,w] * Xs[w][f]  + Xs[t][f] (identity diag term) ----
    float4 xt = Xs[t];
    float t0 = xt.x, t1 = xt.y, t2 = xt.z;
    #pragma unroll
    for (int w = 0; w < V; ++w) {
        float a  = As[t][w];             // conflict-free (pad 65)
        float4 x = Xs[w];                // same address across lanes -> broadcast
        t0 += a * x.x;
        t1 += a * x.y;
        t2 += a * x.z;
    }

    // ---- relu(dinv[t] * t) . W2, then pool over the 64 rows ----
    float y0 = fmaxf(dv * t0, 0.f);
    float y1 = fmaxf(dv * t1, 0.f);
    float y2 = fmaxf(dv * t2, 0.f);
    float r = y0 * W2[0] + y1 * W2[1] + y2 * W2[2];

    #pragma unroll
    for (int off = 32; off >= 1; off >>= 1) r += __shfl_xor(r, off);

    if (t == 0) out[b] = r;
}

extern "C" void kernel_launch(void* const* d_in, const int* in_sizes, int n_in,
                              void* d_out, int out_size, void* d_ws, size_t ws_size,
                              hipStream_t stream) {
    const float* A  = (const float*)d_in[0];
    const float* h0 = (const float*)d_in[1];
    const float* W1 = (const float*)d_in[2];
    const float* W2 = (const float*)d_in[3];
    float* out = (float*)d_out;

    const int B = in_sizes[0] / (V * V);   // 16384
    gcn_fused_kernel<<<B, 64, 0, stream>>>(A, h0, W1, W2, out);
}

// Round 2
// 50.515 us; speedup vs baseline: 1.3851x; 1.3851x over previous
//
#include <hip/hip_runtime.h>
#include <hip/hip_bf16.h>

// Fused GCN: one wave (64 lanes) per batch graph. B=16384, V=64, F_IN=5, F_HID=3.
// A stays entirely in registers (16 float4/lane, coalesced loads); all 16-lane
// reductions use DPP row_shr adds (VALU pipe), so the LDS pipe is ~idle.
//
// Layout: lane t = (g = t>>4, c = t&15). Iteration i covers row r = 4i+g,
// columns 4c..4c+3 (a[i] = A[r, 4c..4c+3]).

#define V 64

template<int CTRL>
__device__ __forceinline__ float dpp_row_add(float x) {
    // x += x shifted within the aligned 16-lane row; out-of-range lanes read 0.
    int s = __builtin_amdgcn_update_dpp(0, __float_as_int(x), CTRL, 0xF, 0xF, true);
    return x + __int_as_float(s);
}

// Sum over each aligned 16-lane group; result valid on lane 15 of the group.
__device__ __forceinline__ float reduce16(float x) {
    x = dpp_row_add<0x111>(x); // row_shr:1
    x = dpp_row_add<0x112>(x); // row_shr:2
    x = dpp_row_add<0x114>(x); // row_shr:4
    x = dpp_row_add<0x118>(x); // row_shr:8
    return x;
}

__global__ __launch_bounds__(64, 3) void gcn_fused_kernel(
    const float* __restrict__ A,     // [B, 64, 64]
    const float* __restrict__ h0,    // [B, 64, 5]
    const float* __restrict__ W1,    // [5, 3]
    const float* __restrict__ W2,    // [3, 1]
    float* __restrict__ out)         // [B]
{
    __shared__ float dinv_lds[V];
    __shared__ float xs_lds[3][V];

    const int b = blockIdx.x;
    const int t = threadIdx.x;
    const int g = t >> 4;
    const int c = t & 15;

    // ---- h0 row for this lane (independent of A; issue early) ----
    const float* h0b = h0 + (size_t)b * (V * 5) + t * 5;
    float h[5];
    #pragma unroll
    for (int k = 0; k < 5; ++k) h[k] = h0b[k];

    // ---- A tile: 16 coalesced float4 loads -> registers ----
    const float4* A4 = reinterpret_cast<const float4*>(A + (size_t)b * (V * V));
    float4 a[16];
    #pragma unroll
    for (int i = 0; i < 16; ++i) a[i] = A4[t + 64 * i];

    // ---- rowsum(adj_hat) -> dinv; register copy (lane15) + LDS for xs step ----
    float dvr[16];
    #pragma unroll
    for (int i = 0; i < 16; ++i) {
        float p = (a[i].x + a[i].y) + (a[i].z + a[i].w);
        p = reduce16(p);
        float dv = rsqrtf(1.0f + p);       // +1 = identity diagonal
        dvr[i] = dv;                        // meaningful on c==15 lanes only
        if (c == 15) dinv_lds[4 * i + g] = dv;
    }

    // ---- xs[t,:] = dinv[t] * (h0[t,:] @ W1) ----
    float dv_t = dinv_lds[t];              // same-wave LDS dependency, no barrier
    float x0 = 0.f, x1 = 0.f, x2 = 0.f;
    #pragma unroll
    for (int k = 0; k < 5; ++k) {
        float hk = h[k];
        x0 += hk * W1[k * 3 + 0];
        x1 += hk * W1[k * 3 + 1];
        x2 += hk * W1[k * 3 + 2];
    }
    xs_lds[0][t] = dv_t * x0;
    xs_lds[1][t] = dv_t * x1;
    xs_lds[2][t] = dv_t * x2;

    // ---- read the 4 xs columns this lane covers, ONCE (reused 16 iters) ----
    float q0[4], q1[4], q2[4];
    #pragma unroll
    for (int j = 0; j < 4; ++j) {
        q0[j] = xs_lds[0][4 * c + j];
        q1[j] = xs_lds[1][4 * c + j];
        q2[j] = xs_lds[2][4 * c + j];
    }
    // identity (A+I): diagonal col of row 4i+g lands on lane c==i, component g
    float xg0 = (g == 0) ? q0[0] : (g == 1) ? q0[1] : (g == 2) ? q0[2] : q0[3];
    float xg1 = (g == 0) ? q1[0] : (g == 1) ? q1[1] : (g == 2) ? q1[2] : q1[3];
    float xg2 = (g == 0) ? q2[0] : (g == 1) ? q2[1] : (g == 2) ? q2[2] : q2[3];

    const float w20 = W2[0], w21 = W2[1], w22 = W2[2];
    float total = 0.f;
    #pragma unroll
    for (int i = 0; i < 16; ++i) {
        float p0 = a[i].x * q0[0] + a[i].y * q0[1] + a[i].z * q0[2] + a[i].w * q0[3];
        float p1 = a[i].x * q1[0] + a[i].y * q1[1] + a[i].z * q1[2] + a[i].w * q1[3];
        float p2 = a[i].x * q2[0] + a[i].y * q2[1] + a[i].z * q2[2] + a[i].w * q2[3];
        bool diag = (c == i);
        p0 += diag ? xg0 : 0.f;
        p1 += diag ? xg1 : 0.f;
        p2 += diag ? xg2 : 0.f;
        p0 = reduce16(p0);
        p1 = reduce16(p1);
        p2 = reduce16(p2);
        float dv = dvr[i];                  // valid on lane15; garbage-but-finite elsewhere
        float y = fmaxf(dv * p0, 0.f) * w20
                + fmaxf(dv * p1, 0.f) * w21
                + fmaxf(dv * p2, 0.f) * w22;
        total += (c == 15) ? y : 0.f;       // each row counted exactly once
    }

    // ---- pool over rows: sum the 4 lane-15 partials (others are 0) ----
    #pragma unroll
    for (int off = 1; off < 64; off <<= 1) total += __shfl_xor(total, off);
    if (t == 0) out[b] = total;
}

extern "C" void kernel_launch(void* const* d_in, const int* in_sizes, int n_in,
                              void* d_out, int out_size, void* d_ws, size_t ws_size,
                              hipStream_t stream) {
    const float* A  = (const float*)d_in[0];
    const float* h0 = (const float*)d_in[1];
    const float* W1 = (const float*)d_in[2];
    const float* W2 = (const float*)d_in[3];
    float* out = (float*)d_out;

    const int B = in_sizes[0] / (V * V);   // 16384
    gcn_fused_kernel<<<B, 64, 0, stream>>>(A, h0, W1, W2, out);
}